// Round 1
// baseline (395.264 us; speedup 1.0000x reference)
//
#include <hip/hip_runtime.h>

// Problem constants (from reference): N=1e6 points, C=32 channels, S=64.
// Key space = 64^4 = 16,777,216 (24-bit keys) -> presence bitmap + popcount
// prefix sum gives rank(key) = index in sorted unique order (jnp.unique).

constexpr int S = 64;
constexpr int KEYSPACE = S * S * S * S;      // 16,777,216
constexpr int NWORDS   = KEYSPACE / 32;      // 524,288 bitmap words
constexpr int SCAN_BLK = 256;                // words per block in prefix kernels
constexpr int NSCANBLK = NWORDS / SCAN_BLK;  // 2048

__device__ __forceinline__ unsigned make_key(int4 c) {
    return (unsigned)(((c.x * S + c.y) * S + c.z) * S + c.w);
}

// Phase 1: mark present keys in the bitmap.
__global__ void k_setbits(const int4* __restrict__ coords,
                          unsigned* __restrict__ bitmap, int n) {
    int i = blockIdx.x * blockDim.x + threadIdx.x;
    if (i < n) {
        unsigned key = make_key(coords[i]);
        atomicOr(&bitmap[key >> 5], 1u << (key & 31));
    }
}

// Phase 2a: per-block (256 words) popcount sums.
__global__ void k_blocksums(const unsigned* __restrict__ bitmap,
                            unsigned* __restrict__ blockSums) {
    int w = blockIdx.x * SCAN_BLK + threadIdx.x;
    unsigned pc = __popc(bitmap[w]);
    // wave64 reduce
    for (int off = 32; off > 0; off >>= 1) pc += __shfl_down(pc, off);
    __shared__ unsigned sm[SCAN_BLK / 64];
    if ((threadIdx.x & 63) == 0) sm[threadIdx.x >> 6] = pc;
    __syncthreads();
    if (threadIdx.x == 0) {
        unsigned s = 0;
        for (int j = 0; j < SCAN_BLK / 64; ++j) s += sm[j];
        blockSums[blockIdx.x] = s;
    }
}

// Phase 2b: exclusive scan of the 2048 block sums (single block, 256 thr x 8).
__global__ void k_scan(const unsigned* __restrict__ blockSums,
                       unsigned* __restrict__ blockOffs) {
    __shared__ unsigned tsum[256];
    int t = threadIdx.x;
    unsigned v[8];
    unsigned s = 0;
    for (int j = 0; j < 8; ++j) { v[j] = blockSums[t * 8 + j]; s += v[j]; }
    tsum[t] = s;
    __syncthreads();
    // naive exclusive scan over 256 thread-sums (LDS broadcast reads, cheap)
    unsigned pre = 0;
    for (int j = 0; j < t; ++j) pre += tsum[j];
    for (int j = 0; j < 8; ++j) { blockOffs[t * 8 + j] = pre; pre += v[j]; }
}

// Phase 2c: per-word exclusive prefix of popcounts.
__global__ void k_wordprefix(const unsigned* __restrict__ bitmap,
                             const unsigned* __restrict__ blockOffs,
                             unsigned* __restrict__ wordPrefix) {
    int t = threadIdx.x;
    int w = blockIdx.x * SCAN_BLK + t;
    unsigned pc = __popc(bitmap[w]);
    __shared__ unsigned sm[SCAN_BLK];
    sm[t] = pc;
    __syncthreads();
    unsigned pre = 0;
    for (int j = 0; j < t; ++j) pre += sm[j];
    wordPrefix[w] = blockOffs[blockIdx.x] + pre;
}

// Phase 3: scatter-add. One lane per (point, channel); 32 lanes share a point
// -> contiguous 128B feature read + contiguous 128B atomicAdd segment.
__global__ void k_scatter(const int4* __restrict__ coords,
                          const float* __restrict__ feats,
                          const unsigned* __restrict__ bitmap,
                          const unsigned* __restrict__ wordPrefix,
                          float* __restrict__ out, int n) {
    long long gid = (long long)blockIdx.x * blockDim.x + threadIdx.x;
    int i = (int)(gid >> 5);
    int c = (int)(gid & 31);
    if (i >= n) return;
    unsigned key = make_key(coords[i]);
    unsigned w = key >> 5, bit = key & 31;
    unsigned rank = wordPrefix[w] + __popc(bitmap[w] & ((1u << bit) - 1u));
    atomicAdd(&out[(long long)rank * 32 + c], feats[(long long)i * 32 + c]);
}

extern "C" void kernel_launch(void* const* d_in, const int* in_sizes, int n_in,
                              void* d_out, int out_size, void* d_ws, size_t ws_size,
                              hipStream_t stream) {
    const int4*  coords = (const int4*)d_in[0];
    const float* feats  = (const float*)d_in[1];
    float* out = (float*)d_out;
    int n = in_sizes[0] / 4;   // coords is [N,4] int32 flat

    // workspace layout (all u32): bitmap[NWORDS] | wordPrefix[NWORDS] |
    //                             blockSums[NSCANBLK] | blockOffs[NSCANBLK]
    unsigned* bitmap     = (unsigned*)d_ws;
    unsigned* wordPrefix = bitmap + NWORDS;
    unsigned* blockSums  = wordPrefix + NWORDS;
    unsigned* blockOffs  = blockSums + NSCANBLK;

    hipMemsetAsync(bitmap, 0, (size_t)NWORDS * sizeof(unsigned), stream);
    hipMemsetAsync(d_out, 0, (size_t)out_size * sizeof(float), stream);

    k_setbits<<<(n + 255) / 256, 256, 0, stream>>>(coords, bitmap, n);
    k_blocksums<<<NSCANBLK, SCAN_BLK, 0, stream>>>(bitmap, blockSums);
    k_scan<<<1, 256, 0, stream>>>(blockSums, blockOffs);
    k_wordprefix<<<NSCANBLK, SCAN_BLK, 0, stream>>>(bitmap, blockOffs, wordPrefix);

    long long tot = (long long)n * 32;
    k_scatter<<<(int)((tot + 255) / 256), 256, 0, stream>>>(
        coords, feats, bitmap, wordPrefix, out, n);
}

// Round 5
// 341.020 us; speedup vs baseline: 1.1591x; 1.1591x over previous
//
#include <hip/hip_runtime.h>

// SCN InputLayer mode=3: dedupe 24-bit voxel keys (64^4 keyspace), scatter-add
// features into sorted-unique rank order. Strategy: presence bitmap + popcount
// prefix-sum gives rank(key); atomicOr-return identifies the unique "winner"
// point per voxel -> winners plain-store (97%), losers atomicAdd (3%) in a
// later dispatch. Only the padding tail of d_out needs zeroing.

constexpr int S = 64;
constexpr int KEYSPACE = S * S * S * S;      // 16,777,216
constexpr int NWORDS   = KEYSPACE / 32;      // 524,288 bitmap words (2 MB)
constexpr int SCAN_BLK = 256;
constexpr int NSCANBLK = NWORDS / SCAN_BLK;  // 2048

// Phase 1: mark presence; record per-point key + win flag (bit 31).
__global__ void k_setbits(const int4* __restrict__ coords,
                          unsigned* __restrict__ bitmap,
                          unsigned* __restrict__ keys, int n) {
    int i = blockIdx.x * blockDim.x + threadIdx.x;
    if (i >= n) return;
    int4 c = coords[i];
    unsigned key = (unsigned)(((c.x * S + c.y) * S + c.z) * S + c.w);
    unsigned bit = 1u << (key & 31);
    unsigned old = atomicOr(&bitmap[key >> 5], bit);
    keys[i] = key | ((old & bit) ? 0u : 0x80000000u);  // bit31 = won the voxel
}

// Phase 2a: per-256-word popcount block sums.
__global__ void k_blocksums(const unsigned* __restrict__ bitmap,
                            unsigned* __restrict__ blockSums) {
    int w = blockIdx.x * SCAN_BLK + threadIdx.x;
    unsigned pc = __popc(bitmap[w]);
    for (int off = 32; off > 0; off >>= 1) pc += __shfl_down(pc, off);
    __shared__ unsigned sm[SCAN_BLK / 64];
    if ((threadIdx.x & 63) == 0) sm[threadIdx.x >> 6] = pc;
    __syncthreads();
    if (threadIdx.x == 0) {
        unsigned s = 0;
        for (int j = 0; j < SCAN_BLK / 64; ++j) s += sm[j];
        blockSums[blockIdx.x] = s;
    }
}

// Phase 2b: exclusive scan of 2048 block sums; also emit total unique count.
__global__ void k_scan(const unsigned* __restrict__ blockSums,
                       unsigned* __restrict__ blockOffs,
                       unsigned* __restrict__ d_total) {
    __shared__ unsigned tsum[256];
    int t = threadIdx.x;
    unsigned v[8];
    unsigned s = 0;
    for (int j = 0; j < 8; ++j) { v[j] = blockSums[t * 8 + j]; s += v[j]; }
    tsum[t] = s;
    __syncthreads();
    unsigned pre = 0;
    for (int j = 0; j < t; ++j) pre += tsum[j];
    for (int j = 0; j < 8; ++j) { blockOffs[t * 8 + j] = pre; pre += v[j]; }
    if (t == 255) d_total[0] = pre;   // total #unique keys
}

// Phase 2c: per-word prefix via shuffle scan; pack {bits, prefix} -> uint2.
__global__ void k_meta(const unsigned* __restrict__ bitmap,
                       const unsigned* __restrict__ blockOffs,
                       uint2* __restrict__ meta) {
    int t = threadIdx.x;
    int w = blockIdx.x * SCAN_BLK + t;
    unsigned bits = bitmap[w];
    unsigned pc = __popc(bits);
    unsigned inc = pc;                      // wave-inclusive scan (64 lanes)
    for (int off = 1; off < 64; off <<= 1) {
        unsigned x = __shfl_up(inc, off);
        if ((t & 63) >= off) inc += x;
    }
    __shared__ unsigned wsum[SCAN_BLK / 64];
    if ((t & 63) == 63) wsum[t >> 6] = inc;
    __syncthreads();
    unsigned base = 0;
    for (int j = 0; j < (t >> 6); ++j) base += wsum[j];
    meta[w] = make_uint2(bits, blockOffs[blockIdx.x] + base + (inc - pc));
}

// Phase 3a: winners plain-store their row (covers every unique row once).
// 8 lanes per point, float4 per lane -> 16B/lane coalesced in and out.
__global__ void k_scatter1(const unsigned* __restrict__ keys,
                           const float4* __restrict__ feats4,
                           const uint2* __restrict__ meta,
                           float4* __restrict__ out4, int n) {
    int gid = blockIdx.x * blockDim.x + threadIdx.x;
    int i = gid >> 3;
    if (i >= n) return;
    unsigned kw = keys[i];
    if (!(kw & 0x80000000u)) return;        // loser: handled in scatter2
    unsigned key = kw & 0x00FFFFFFu;
    uint2 m = meta[key >> 5];
    unsigned rank = m.y + __popc(m.x & ((1u << (key & 31)) - 1u));
    int c4 = gid & 7;
    out4[(long long)rank * 8 + c4] = feats4[(long long)i * 8 + c4];
}

// Phase 3b: losers (~3%) atomicAdd on top of the winner's store.
__global__ void k_scatter2(const unsigned* __restrict__ keys,
                           const float* __restrict__ feats,
                           const uint2* __restrict__ meta,
                           float* __restrict__ out, int n) {
    int i = blockIdx.x * blockDim.x + threadIdx.x;
    if (i >= n) return;
    unsigned kw = keys[i];
    if (kw & 0x80000000u) return;
    unsigned key = kw & 0x00FFFFFFu;
    uint2 m = meta[key >> 5];
    unsigned rank = m.y + __popc(m.x & ((1u << (key & 31)) - 1u));
    const float* f = feats + (long long)i * 32;
    float* o = out + (long long)rank * 32;
#pragma unroll
    for (int c = 0; c < 32; ++c) atomicAdd(&o[c], f[c]);
}

// Phase 4: zero only the padding tail rows [nUnique, n).
__global__ void k_tailzero(float4* __restrict__ out4,
                           const unsigned* __restrict__ d_total, int n) {
    unsigned nU = *d_total;
    long long start = (long long)nU * 8;
    long long end   = (long long)n * 8;
    long long stride = (long long)gridDim.x * blockDim.x;
    for (long long idx = start + blockIdx.x * (long long)blockDim.x + threadIdx.x;
         idx < end; idx += stride)
        out4[idx] = make_float4(0.f, 0.f, 0.f, 0.f);
}

extern "C" void kernel_launch(void* const* d_in, const int* in_sizes, int n_in,
                              void* d_out, int out_size, void* d_ws, size_t ws_size,
                              hipStream_t stream) {
    const int4*   coords = (const int4*)d_in[0];
    const float*  feats  = (const float*)d_in[1];
    const float4* feats4 = (const float4*)d_in[1];
    float*  out  = (float*)d_out;
    float4* out4 = (float4*)d_out;
    int n = in_sizes[0] / 4;
    if (n <= 0) return;

    // ws layout (u32): bitmap[NWORDS] | meta[2*NWORDS] | keys[n] |
    //                  blockSums[NSCANBLK] | blockOffs[NSCANBLK] | total[1]
    unsigned* bitmap    = (unsigned*)d_ws;
    uint2*    meta      = (uint2*)(bitmap + NWORDS);
    unsigned* keys      = bitmap + NWORDS + 2 * NWORDS;
    unsigned* blockSums = keys + n;
    unsigned* blockOffs = blockSums + NSCANBLK;
    unsigned* d_total   = blockOffs + NSCANBLK;

    hipMemsetAsync(bitmap, 0, (size_t)NWORDS * sizeof(unsigned), stream);

    k_setbits<<<(n + 255) / 256, 256, 0, stream>>>(coords, bitmap, keys, n);
    k_blocksums<<<NSCANBLK, SCAN_BLK, 0, stream>>>(bitmap, blockSums);
    k_scan<<<1, 256, 0, stream>>>(blockSums, blockOffs, d_total);
    k_meta<<<NSCANBLK, SCAN_BLK, 0, stream>>>(bitmap, blockOffs, meta);

    long long lanes = (long long)n * 8;
    k_scatter1<<<(int)((lanes + 255) / 256), 256, 0, stream>>>(keys, feats4, meta, out4, n);
    k_scatter2<<<(n + 255) / 256, 256, 0, stream>>>(keys, feats, meta, out, n);
    k_tailzero<<<512, 256, 0, stream>>>(out4, d_total, n);
}